// Round 10
// baseline (386.210 us; speedup 1.0000x reference)
//
#include <hip/hip_runtime.h>
#include <math.h>

#define NPOS 131072  // 8*128*128 spatial positions per (b, channel)

// ---------------------------------------------------------------------------
// k_prep: transpose w_qkv [192 out][64 in] -> wT[3 g][64 k][64 o].
// ---------------------------------------------------------------------------
__global__ void k_prep(const float* __restrict__ w_qkv, float* __restrict__ wT) {
  for (int i = blockIdx.x * 256 + threadIdx.x; i < 12288; i += 512) {
    int g = i >> 12, r = i & 4095, k = r >> 6, o = r & 63;
    wT[i] = w_qkv[(g * 64 + o) * 64 + k];
  }
}

// ---------------------------------------------------------------------------
// k_pw: pre[b][o][p] = sum_k wTg[k][o] * x[b][k][p].  grid (512, 2), block 256.
// ---------------------------------------------------------------------------
__global__ __launch_bounds__(256) void k_pw(const float* __restrict__ x,
                                            const float* __restrict__ wTg,
                                            float* __restrict__ pre) {
  const int p = blockIdx.x * 256 + threadIdx.x;
  const int b = blockIdx.y;
  float acc[64];
#pragma unroll
  for (int o = 0; o < 64; ++o) acc[o] = 0.f;
  const float* xb = x + ((size_t)b * 64) * NPOS + p;
  for (int k = 0; k < 64; ++k) {
    float xv = xb[(size_t)k * NPOS];
    const float* wr = wTg + (k << 6);   // wave-uniform row -> s_load
#pragma unroll
    for (int o = 0; o < 64; ++o) acc[o] = fmaf(wr[o], xv, acc[o]);
  }
  float* ob = pre + ((size_t)b * 64) * NPOS + p;
#pragma unroll
  for (int o = 0; o < 64; ++o) ob[(size_t)o * NPOS] = acc[o];
}

// ---------------------------------------------------------------------------
// stage_tile: one channel's halo tile -> LDS t[10][10][40]. float4 center,
// scalar edges, zero d-halo planes.
// ---------------------------------------------------------------------------
__device__ __forceinline__ void stage_tile(float (*t)[10][40], const float* __restrict__ in,
                                           int h0, int w0, int tid) {
  for (int i = tid; i < 800; i += 256) {
    int j = i & 7, row = i >> 3;
    int h = row % 10, dpl = row / 10;
    int dd = dpl - 1, hh = h0 + h - 1;
    float4 v = make_float4(0.f, 0.f, 0.f, 0.f);
    if (dd >= 0 && dd < 8 && hh >= 0 && hh < 128)
      v = *(const float4*)&in[((size_t)dd * 128 + hh) * 128 + (w0 + j * 4)];
    *(float4*)&t[dpl][h][4 + j * 4] = v;
  }
  for (int i = tid; i < 200; i += 256) {
    int side = i & 1, row = i >> 1;
    int h = row % 10, dpl = row / 10;
    int dd = dpl - 1, hh = h0 + h - 1;
    int ww = side ? (w0 + 32) : (w0 - 1);
    float v = 0.f;
    if (dd >= 0 && dd < 8 && hh >= 0 && hh < 128 && ww >= 0 && ww < 128)
      v = in[((size_t)dd * 128 + hh) * 128 + ww];
    t[dpl][h][side ? 36 : 3] = v;
  }
}

// ---------------------------------------------------------------------------
// conv_droll: d-rolling 3x3x3 conv: 90 LDS reads, 216 FMA for 8 d-outputs.
// ---------------------------------------------------------------------------
__device__ __forceinline__ void conv_droll(const float (*t)[10][40], const float* wk,
                                           int hl, int wl, float* acc) {
#pragma unroll
  for (int d = 0; d < 8; ++d) acc[d] = 0.f;
#pragma unroll
  for (int dpl = 0; dpl < 10; ++dpl) {
#pragma unroll
    for (int kh = 0; kh < 3; ++kh) {
#pragma unroll
      for (int kw = 0; kw < 3; ++kw) {
        float f = t[dpl][hl + kh][3 + wl + kw];
#pragma unroll
        for (int kd = 0; kd < 3; ++kd) {
          const int d = dpl - kd;
          if (d >= 0 && d < 8)
            acc[d] = fmaf(f, wk[(kd * 3 + kh) * 3 + kw], acc[d]);
        }
      }
    }
  }
}

// ---------------------------------------------------------------------------
// k_dw: depthwise 3x3x3 SAME on a 64-channel group. Flat grid 8192,
// XCD-swizzled. block (32, 8). Optional sum-of-squares partials -> nqp.
// ---------------------------------------------------------------------------
__global__ __launch_bounds__(256) void k_dw(const float* __restrict__ pre,
                                            const float* __restrict__ w_dw,
                                            float* __restrict__ conv,
                                            float* __restrict__ nqp, int g) {
  const int id = blockIdx.x;
  const int sid = (id & 7) * 1024 + (id >> 3);
  const int z = sid >> 6, r = sid & 63, by = r >> 2, bx = r & 3;
  const int b = z >> 6;
  const int c = z & 63;
  const int h0 = by * 8;
  const int w0 = bx * 32;
  __shared__ float t[10][10][40];
  __shared__ float red[4];
  const int tid = threadIdx.y * 32 + threadIdx.x;
  stage_tile(t, pre + ((size_t)b * 64 + c) * NPOS, h0, w0, tid);
  float wk[27];
#pragma unroll
  for (int i = 0; i < 27; ++i) wk[i] = w_dw[(g * 64 + c) * 27 + i];
  __syncthreads();
  const int wl = threadIdx.x, hl = threadIdx.y;
  float acc[8];
  conv_droll(t, wk, hl, wl, acc);
  float* outp = conv + ((size_t)b * 64 + c) * NPOS + (size_t)(h0 + hl) * 128 + (w0 + wl);
  float nsum = 0.f;
#pragma unroll
  for (int d = 0; d < 8; ++d) {
    outp[(size_t)d * 16384] = acc[d];
    nsum = fmaf(acc[d], acc[d], nsum);
  }
  if (nqp) {
    const int lane = tid & 63, wv = tid >> 6;
    float v = nsum;
    v += __shfl_down(v, 32); v += __shfl_down(v, 16); v += __shfl_down(v, 8);
    v += __shfl_down(v, 4);  v += __shfl_down(v, 2);  v += __shfl_down(v, 1);
    if (lane == 0) red[wv] = v;
    __syncthreads();
    if (tid == 0) {
      const int blk = by * 4 + bx;
      nqp[((size_t)b * 64 + c) * 64 + blk] = red[0] + red[1] + red[2] + red[3];
    }
  }
}

#define GCHUNKS 256  // gram2 position chunks per (b,head): 512 positions each

// ---------------------------------------------------------------------------
// k_gram2: streaming Gram reduce. grid (GCHUNKS, 16 bh), block 256; each
// thread 2 fully-unrolled iterations (32 independent loads up front -> 160
// FMA). 4096 blocks = 16 blocks/CU demand: TLP hides load latency (r9: 1024
// blocks -> 25% occupancy, VALUBusy 10%, latency-bound at 66us).
// partial9[((b*64+ch)*GCHUNKS + chunk)*9 + j]: j<8 -> S[c=j][e], j==8 -> nk[e].
// ---------------------------------------------------------------------------
__global__ __launch_bounds__(256) void k_gram2(const float* __restrict__ qconv,
                                               const float* __restrict__ kconv,
                                               float* __restrict__ partial9) {
  const int chunk = blockIdx.x;   // 0..GCHUNKS-1
  const int bh = blockIdx.y;      // 0..15
  const int b = bh >> 3, head = bh & 7;
  const int tid = threadIdx.x;
  const size_t base = ((size_t)b * 64 + head * 8) * NPOS + (size_t)chunk * 512 + tid;
  const float* qb = qconv + base;
  const float* kb = kconv + base;
  float S[64], nk[8];
#pragma unroll
  for (int i = 0; i < 64; ++i) S[i] = 0.f;
#pragma unroll
  for (int i = 0; i < 8; ++i) nk[i] = 0.f;
#pragma unroll
  for (int it = 0; it < 2; ++it) {
    const size_t off = (size_t)it * 256;
    float qv[8], kv[8];
#pragma unroll
    for (int c = 0; c < 8; ++c) qv[c] = qb[(size_t)c * NPOS + off];
#pragma unroll
    for (int e = 0; e < 8; ++e) kv[e] = kb[(size_t)e * NPOS + off];
#pragma unroll
    for (int e = 0; e < 8; ++e) nk[e] = fmaf(kv[e], kv[e], nk[e]);
#pragma unroll
    for (int c = 0; c < 8; ++c)
#pragma unroll
      for (int e = 0; e < 8; ++e) S[c * 8 + e] = fmaf(qv[c], kv[e], S[c * 8 + e]);
  }
  __shared__ float red[4][72];
  __shared__ float sums[72];
  const int lane = tid & 63, wv = tid >> 6;
#pragma unroll
  for (int i = 0; i < 72; ++i) {
    float v = (i < 64) ? S[i] : nk[i - 64];
    v += __shfl_down(v, 32); v += __shfl_down(v, 16); v += __shfl_down(v, 8);
    v += __shfl_down(v, 4);  v += __shfl_down(v, 2);  v += __shfl_down(v, 1);
    if (lane == 0) red[wv][i] = v;
  }
  __syncthreads();
  if (tid < 72) sums[tid] = red[0][tid] + red[1][tid] + red[2][tid] + red[3][tid];
  __syncthreads();
  if (tid < 72) {
    const int e = tid / 9, j = tid % 9;
    float val = (j < 8) ? sums[j * 8 + e] : sums[64 + e];
    partial9[(((size_t)b * 64 + head * 8 + e) * GCHUNKS + chunk) * 9 + j] = val;
  }
}

// ---------------------------------------------------------------------------
// k_gram (fallback, ws too small for kconv): r8's fused dw+gram.
// partial9 indexed with 64 chunks in fallback; k_attn handles both via NCH.
// ---------------------------------------------------------------------------
__global__ __launch_bounds__(256) void k_gram(const float* __restrict__ kpre,
                                              const float* __restrict__ qconv,
                                              const float* __restrict__ w_dw,
                                              float* __restrict__ partial9) {
  const int i = blockIdx.x;
  const int slot = i & 7, j = i >> 3;
  const int hg = slot * 2 + (j >> 9);
  const int ch8 = (j >> 6) & 7;
  const int blk = j & 63;
  const int b = hg >> 3, head = hg & 7;
  const int ch = head * 8 + ch8;
  const int by = blk >> 2, bx = blk & 3;
  const int h0 = by * 8;
  const int w0 = bx * 32;
  __shared__ float t[10][10][40];
  __shared__ float red[4][9];
  const int tid = threadIdx.y * 32 + threadIdx.x;
  const int wl = threadIdx.x, hl = threadIdx.y;
  stage_tile(t, kpre + ((size_t)b * 64 + ch) * NPOS, h0, w0, tid);
  float wk[27];
#pragma unroll
  for (int i2 = 0; i2 < 27; ++i2) wk[i2] = w_dw[(64 + ch) * 27 + i2];
  float qv[64];
  {
    const float* qb = qconv + ((size_t)b * 64 + head * 8) * NPOS +
                      (size_t)(h0 + hl) * 128 + (w0 + wl);
#pragma unroll
    for (int c = 0; c < 8; ++c)
#pragma unroll
      for (int d = 0; d < 8; ++d)
        qv[c * 8 + d] = qb[(size_t)c * NPOS + (size_t)d * 16384];
  }
  __builtin_amdgcn_sched_barrier(0);
  __syncthreads();
  float a[8];
  conv_droll(t, wk, hl, wl, a);
  float nk = 0.f;
#pragma unroll
  for (int d = 0; d < 8; ++d) nk = fmaf(a[d], a[d], nk);
  float S[8];
#pragma unroll
  for (int c = 0; c < 8; ++c) {
    float s = 0.f;
#pragma unroll
    for (int d = 0; d < 8; ++d) s = fmaf(qv[c * 8 + d], a[d], s);
    S[c] = s;
  }
  const int lane = tid & 63, wv = tid >> 6;
#pragma unroll
  for (int i2 = 0; i2 < 9; ++i2) {
    float v = (i2 < 8) ? S[i2] : nk;
    v += __shfl_down(v, 32); v += __shfl_down(v, 16); v += __shfl_down(v, 8);
    v += __shfl_down(v, 4);  v += __shfl_down(v, 2);  v += __shfl_down(v, 1);
    if (lane == 0) red[wv][i2] = v;
  }
  __syncthreads();
  if (tid < 9) {
    float s = red[0][tid] + red[1][tid] + red[2][tid] + red[3][tid];
    partial9[(((size_t)b * 64 + ch) * 64 + blk) * 9 + tid] = s;
  }
}

// ---------------------------------------------------------------------------
// k_attn: reduce partials (NCH chunks), l2-normalize, temperature, softmax.
// grid 16, block 128.
// ---------------------------------------------------------------------------
__global__ void k_attn(const float* __restrict__ partial9, const float* __restrict__ nqp,
                       const float* __restrict__ temp, float* __restrict__ A, int NCH) {
  const int bh = blockIdx.x;
  const int b = bh >> 3, head = bh & 7;
  const int tid = threadIdx.x;
  __shared__ float sums[80];
  if (tid < 64) {
    const int c = tid >> 3, e = tid & 7;
    float s = 0.f;
    const float* pp = partial9 + (((size_t)b * 64 + head * 8 + e) * NCH) * 9 + c;
    for (int j = 0; j < NCH; ++j) s += pp[j * 9];
    sums[c * 8 + e] = s;
  } else if (tid < 72) {
    const int e = tid - 64;
    float s = 0.f;
    const float* pp = partial9 + (((size_t)b * 64 + head * 8 + e) * NCH) * 9 + 8;
    for (int j = 0; j < NCH; ++j) s += pp[j * 9];
    sums[64 + e] = s;  // nk[e]
  } else if (tid < 80) {
    const int c = tid - 72;
    float s = 0.f;
    const float* pp = nqp + ((size_t)b * 64 + head * 8 + c) * 64;
    for (int j = 0; j < 64; ++j) s += pp[j];
    sums[72 + c] = s;  // nq[c]
  }
  __syncthreads();
  if (tid < 8) {
    const int c = tid;
    float tp = temp[head];
    float qd = fmaxf(sqrtf(sums[72 + c]), 1e-12f);
    float vals[8];
    float mx = -1e30f;
#pragma unroll
    for (int e = 0; e < 8; ++e) {
      float kd = fmaxf(sqrtf(sums[64 + e]), 1e-12f);
      vals[e] = sums[c * 8 + e] / (qd * kd) * tp;
      mx = fmaxf(mx, vals[e]);
    }
    float den = 0.f;
#pragma unroll
    for (int e = 0; e < 8; ++e) { vals[e] = expf(vals[e] - mx); den += vals[e]; }
#pragma unroll
    for (int e = 0; e < 8; ++e) A[bh * 64 + c * 8 + e] = vals[e] / den;
  }
}

// ---------------------------------------------------------------------------
// k_M: fold softmax(A) into W_proj -> MT[b][g][o] (transposed for s_load).
// ---------------------------------------------------------------------------
__global__ void k_M(const float* __restrict__ w_proj, const float* __restrict__ A,
                    float* __restrict__ MT) {
  const int b = blockIdx.x;
  for (int e = threadIdx.x; e < 4096; e += 256) {
    int o = e >> 6, gch = e & 63;
    int hg = gch >> 3, j = gch & 7;
    float s = 0.f;
#pragma unroll
    for (int i = 0; i < 8; ++i)
      s += w_proj[o * 64 + hg * 8 + i] * A[(b * 8 + hg) * 64 + i * 8 + j];
    MT[b * 4096 + gch * 64 + o] = s;
  }
}

// ---------------------------------------------------------------------------
// k_out: out[b][o][p] = sum_g MT[b][g][o] * vconv[b][g][p]. grid (512, 2).
// ---------------------------------------------------------------------------
__global__ __launch_bounds__(256) void k_out(const float* __restrict__ vconv,
                                             const float* __restrict__ MT,
                                             float* __restrict__ out) {
  const int p = blockIdx.x * 256 + threadIdx.x;
  const int b = blockIdx.y;
  float acc[64];
#pragma unroll
  for (int o = 0; o < 64; ++o) acc[o] = 0.f;
  const float* vb = vconv + ((size_t)b * 64) * NPOS + p;
  const float* Mb = MT + b * 4096;
  for (int g = 0; g < 64; ++g) {
    float vv = vb[(size_t)g * NPOS];
    const float* wr = Mb + (g << 6);
#pragma unroll
    for (int o = 0; o < 64; ++o) acc[o] = fmaf(wr[o], vv, acc[o]);
  }
  float* ob = out + ((size_t)b * 64) * NPOS + p;
#pragma unroll
  for (int o = 0; o < 64; ++o) ob[(size_t)o * NPOS] = acc[o];
}

extern "C" void kernel_launch(void* const* d_in, const int* in_sizes, int n_in,
                              void* d_out, int out_size, void* d_ws, size_t ws_size,
                              hipStream_t stream) {
  const float* x      = (const float*)d_in[0];
  const float* w_qkv  = (const float*)d_in[1];
  const float* w_dw   = (const float*)d_in[2];
  const float* temp   = (const float*)d_in[3];
  const float* w_proj = (const float*)d_in[4];
  float* out = (float*)d_out;   // also used as pre-conv staging per group
  float* ws  = (float*)d_ws;

  // Two-stage path needs qconv + kconv live simultaneously (~135.5 MB).
  // (ws_size is ~256 MiB: r1 overflowed it at 269.8 MB, r9's 134.6 MB passed.)
  const size_t P9 = 128ull * GCHUNKS * 9;  // 294,912 floats
  const size_t need2 = (2ull * 16777216ull + 8192 + P9 + 1024 + 8192 + 12288) * 4ull;
  const bool twostage = ws_size >= need2;

  float* conv_buf = ws;                         // qconv, later vconv (67 MB)
  float* kconv    = conv_buf + 16777216ull;     // two-stage only (67 MB)
  float* tail     = twostage ? (kconv + 16777216ull) : kconv;
  float* nqp      = tail;                       // 8,192
  float* partial9 = nqp + 8192ull;              // P9 (two-stage) / 73,728 (fallback)
  float* Abuf     = partial9 + P9;              // 1,024
  float* MTbuf    = Abuf + 1024ull;             // 8,192
  float* wTbuf    = MTbuf + 8192ull;            // 12,288

  k_prep<<<2, 256, 0, stream>>>(w_qkv, wTbuf);
  // q group: pointwise -> d_out, depthwise -> conv_buf (+ nq partials)
  k_pw<<<dim3(512, 2), 256, 0, stream>>>(x, wTbuf, out);
  k_dw<<<8192, dim3(32, 8), 0, stream>>>(out, w_dw, conv_buf, nqp, 0);
  // k group: pointwise -> d_out
  k_pw<<<dim3(512, 2), 256, 0, stream>>>(x, wTbuf + 4096, out);
  if (twostage) {
    k_dw<<<8192, dim3(32, 8), 0, stream>>>(out, w_dw, kconv, nullptr, 1);
    k_gram2<<<dim3(GCHUNKS, 16), 256, 0, stream>>>(conv_buf, kconv, partial9);
    k_attn<<<16, 128, 0, stream>>>(partial9, nqp, temp, Abuf, GCHUNKS);
  } else {
    k_gram<<<8192, dim3(32, 8), 0, stream>>>(out, conv_buf, w_dw, partial9);
    k_attn<<<16, 128, 0, stream>>>(partial9, nqp, temp, Abuf, 64);
  }
  k_M<<<2, 256, 0, stream>>>(w_proj, Abuf, MTbuf);
  // v group: pointwise -> d_out, depthwise -> conv_buf, apply M -> d_out
  k_pw<<<dim3(512, 2), 256, 0, stream>>>(x, wTbuf + 8192, out);
  k_dw<<<8192, dim3(32, 8), 0, stream>>>(out, w_dw, conv_buf, nullptr, 2);
  k_out<<<dim3(512, 2), 256, 0, stream>>>(conv_buf, MTbuf, out);
}

// Round 11
// 288.605 us; speedup vs baseline: 1.3382x; 1.3382x over previous
//
#include <hip/hip_runtime.h>
#include <math.h>

#define NPOS 131072  // 8*128*128 spatial positions per (b, channel)
#define GC 128       // gram chunks per (b,head); chunk = 1024 positions

// ---------------------------------------------------------------------------
// k_prep: transpose w_qkv [192 out][64 in] -> wT[3 g][64 k][64 o].
// ---------------------------------------------------------------------------
__global__ void k_prep(const float* __restrict__ w_qkv, float* __restrict__ wT) {
  for (int i = blockIdx.x * 256 + threadIdx.x; i < 12288; i += 512) {
    int g = i >> 12, r = i & 4095, k = r >> 6, o = r & 63;
    wT[i] = w_qkv[(g * 64 + o) * 64 + k];
  }
}

// ---------------------------------------------------------------------------
// k_pw: pre[b][o][p] = sum_k wTg[k][o] * x[b][k][p].  grid (512, 2), block 256.
// ---------------------------------------------------------------------------
__global__ __launch_bounds__(256) void k_pw(const float* __restrict__ x,
                                            const float* __restrict__ wTg,
                                            float* __restrict__ pre) {
  const int p = blockIdx.x * 256 + threadIdx.x;
  const int b = blockIdx.y;
  float acc[64];
#pragma unroll
  for (int o = 0; o < 64; ++o) acc[o] = 0.f;
  const float* xb = x + ((size_t)b * 64) * NPOS + p;
  for (int k = 0; k < 64; ++k) {
    float xv = xb[(size_t)k * NPOS];
    const float* wr = wTg + (k << 6);   // wave-uniform row -> s_load
#pragma unroll
    for (int o = 0; o < 64; ++o) acc[o] = fmaf(wr[o], xv, acc[o]);
  }
  float* ob = pre + ((size_t)b * 64) * NPOS + p;
#pragma unroll
  for (int o = 0; o < 64; ++o) ob[(size_t)o * NPOS] = acc[o];
}

// ---------------------------------------------------------------------------
// stage_tile: one channel's halo tile -> LDS t[10][10][40]. float4 center,
// scalar edges, zero d-halo planes.
// ---------------------------------------------------------------------------
__device__ __forceinline__ void stage_tile(float (*t)[10][40], const float* __restrict__ in,
                                           int h0, int w0, int tid) {
  for (int i = tid; i < 800; i += 256) {
    int j = i & 7, row = i >> 3;
    int h = row % 10, dpl = row / 10;
    int dd = dpl - 1, hh = h0 + h - 1;
    float4 v = make_float4(0.f, 0.f, 0.f, 0.f);
    if (dd >= 0 && dd < 8 && hh >= 0 && hh < 128)
      v = *(const float4*)&in[((size_t)dd * 128 + hh) * 128 + (w0 + j * 4)];
    *(float4*)&t[dpl][h][4 + j * 4] = v;
  }
  for (int i = tid; i < 200; i += 256) {
    int side = i & 1, row = i >> 1;
    int h = row % 10, dpl = row / 10;
    int dd = dpl - 1, hh = h0 + h - 1;
    int ww = side ? (w0 + 32) : (w0 - 1);
    float v = 0.f;
    if (dd >= 0 && dd < 8 && hh >= 0 && hh < 128 && ww >= 0 && ww < 128)
      v = in[((size_t)dd * 128 + hh) * 128 + ww];
    t[dpl][h][side ? 36 : 3] = v;
  }
}

// ---------------------------------------------------------------------------
// conv_droll: d-rolling 3x3x3 conv: 90 LDS reads, 216 FMA for 8 d-outputs.
// ---------------------------------------------------------------------------
__device__ __forceinline__ void conv_droll(const float (*t)[10][40], const float* wk,
                                           int hl, int wl, float* acc) {
#pragma unroll
  for (int d = 0; d < 8; ++d) acc[d] = 0.f;
#pragma unroll
  for (int dpl = 0; dpl < 10; ++dpl) {
#pragma unroll
    for (int kh = 0; kh < 3; ++kh) {
#pragma unroll
      for (int kw = 0; kw < 3; ++kw) {
        float f = t[dpl][hl + kh][3 + wl + kw];
#pragma unroll
        for (int kd = 0; kd < 3; ++kd) {
          const int d = dpl - kd;
          if (d >= 0 && d < 8)
            acc[d] = fmaf(f, wk[(kd * 3 + kh) * 3 + kw], acc[d]);
        }
      }
    }
  }
}

// ---------------------------------------------------------------------------
// k_dw: depthwise 3x3x3 SAME on a 64-channel group. Flat grid 8192,
// XCD-swizzled. block (32, 8). Optional sum-of-squares partials -> nsq
// (used for q-norms AND k-norms; removes nk from the gram kernel).
// ---------------------------------------------------------------------------
__global__ __launch_bounds__(256) void k_dw(const float* __restrict__ pre,
                                            const float* __restrict__ w_dw,
                                            float* __restrict__ conv,
                                            float* __restrict__ nsq, int g) {
  const int id = blockIdx.x;
  const int sid = (id & 7) * 1024 + (id >> 3);
  const int z = sid >> 6, r = sid & 63, by = r >> 2, bx = r & 3;
  const int b = z >> 6;
  const int c = z & 63;
  const int h0 = by * 8;
  const int w0 = bx * 32;
  __shared__ float t[10][10][40];
  __shared__ float red[4];
  const int tid = threadIdx.y * 32 + threadIdx.x;
  stage_tile(t, pre + ((size_t)b * 64 + c) * NPOS, h0, w0, tid);
  float wk[27];
#pragma unroll
  for (int i = 0; i < 27; ++i) wk[i] = w_dw[(g * 64 + c) * 27 + i];
  __syncthreads();
  const int wl = threadIdx.x, hl = threadIdx.y;
  float acc[8];
  conv_droll(t, wk, hl, wl, acc);
  float* outp = conv + ((size_t)b * 64 + c) * NPOS + (size_t)(h0 + hl) * 128 + (w0 + wl);
  float nsum = 0.f;
#pragma unroll
  for (int d = 0; d < 8; ++d) {
    outp[(size_t)d * 16384] = acc[d];
    nsum = fmaf(acc[d], acc[d], nsum);
  }
  if (nsq) {
    const int lane = tid & 63, wv = tid >> 6;
    float v = nsum;
    v += __shfl_down(v, 32); v += __shfl_down(v, 16); v += __shfl_down(v, 8);
    v += __shfl_down(v, 4);  v += __shfl_down(v, 2);  v += __shfl_down(v, 1);
    if (lane == 0) red[wv] = v;
    __syncthreads();
    if (tid == 0) {
      const int blk = by * 4 + bx;
      nsq[((size_t)b * 64 + c) * 64 + blk] = red[0] + red[1] + red[2] + red[3];
    }
  }
}

// ---------------------------------------------------------------------------
// k_gramS: streaming Gram reduce, S[8][8] only (norms come from k_dw).
// grid (GC, 16 bh), block 256; each thread 4 unrolled iterations of
// {16 coalesced loads -> 64 FMA}. asm guards pin S in VGPRs (r10: compiler
// rematerialized S lazily -> VGPR 28 and 432 bpermutes/thread).
// Reduction: butterfly-SPLIT — each xor step halves the ARRAY across lane
// pairs (63 shuffles total vs 64x6=384): lane l ends with full wave sum of
// S[bitrev6(l)].
// partialS[(bh*GC + chunk)*64 + c*8+e].
// ---------------------------------------------------------------------------
__global__ __launch_bounds__(256) void k_gramS(const float* __restrict__ qconv,
                                               const float* __restrict__ kconv,
                                               float* __restrict__ partialS) {
  const int chunk = blockIdx.x;   // 0..GC-1
  const int bh = blockIdx.y;      // 0..15
  const int b = bh >> 3, head = bh & 7;
  const int tid = threadIdx.x;
  const size_t base = ((size_t)b * 64 + head * 8) * NPOS + (size_t)chunk * 1024 + tid;
  const float* qb = qconv + base;
  const float* kb = kconv + base;
  float S[64];
#pragma unroll
  for (int i = 0; i < 64; ++i) S[i] = 0.f;
#pragma unroll
  for (int it = 0; it < 4; ++it) {
    const size_t off = (size_t)it * 256;
    float qv[8], kv[8];
#pragma unroll
    for (int c = 0; c < 8; ++c) qv[c] = qb[(size_t)c * NPOS + off];
#pragma unroll
    for (int e = 0; e < 8; ++e) kv[e] = kb[(size_t)e * NPOS + off];
#pragma unroll
    for (int c = 0; c < 8; ++c)
#pragma unroll
      for (int e = 0; e < 8; ++e) S[c * 8 + e] = fmaf(qv[c], kv[e], S[c * 8 + e]);
  }
#pragma unroll
  for (int i = 0; i < 64; ++i) asm volatile("" : "+v"(S[i]));  // keep S material

  const int lane = tid & 63, wv = tid >> 6;
#define BSTEP(src, dst, n, s)                                        \
  {                                                                  \
    const bool hi_ = (lane >> (s)) & 1;                              \
    _Pragma("unroll")                                                \
    for (int i_ = 0; i_ < (n); ++i_) {                               \
      float send_ = hi_ ? src[i_] : src[i_ + (n)];                   \
      float mine_ = hi_ ? src[i_ + (n)] : src[i_];                   \
      dst[i_] = mine_ + __shfl_xor(send_, 1 << (s));                 \
    }                                                                \
  }
  float v32[32], v16[16], v8[8], v4[4], v2[2], v1[1];
  BSTEP(S,   v32, 32, 0)
  BSTEP(v32, v16, 16, 1)
  BSTEP(v16, v8,   8, 2)
  BSTEP(v8,  v4,   4, 3)
  BSTEP(v4,  v2,   2, 4)
  BSTEP(v2,  v1,   1, 5)
#undef BSTEP
  // lane l holds wave-total of S[bitrev6(l)]
  const int idx = ((lane & 1) << 5) | ((lane & 2) << 3) | ((lane & 4) << 1) |
                  ((lane & 8) >> 1) | ((lane & 16) >> 3) | ((lane & 32) >> 5);
  __shared__ float red[4][64];
  red[wv][idx] = v1[0];
  __syncthreads();
  if (tid < 64) {
    float s = red[0][tid] + red[1][tid] + red[2][tid] + red[3][tid];
    partialS[((size_t)bh * GC + chunk) * 64 + tid] = s;
  }
}

// ---------------------------------------------------------------------------
// k_attn: reduce partialS (GC chunks) + nqp/nkp (64 spatial blocks),
// l2-normalize, temperature, softmax -> A[bh][c][e]. grid 16, block 128.
// ---------------------------------------------------------------------------
__global__ void k_attn(const float* __restrict__ partialS, const float* __restrict__ nqp,
                       const float* __restrict__ nkp, const float* __restrict__ temp,
                       float* __restrict__ A) {
  const int bh = blockIdx.x;
  const int b = bh >> 3, head = bh & 7;
  const int tid = threadIdx.x;
  __shared__ float sums[80];
  if (tid < 64) {
    float s = 0.f;
    const float* pp = partialS + (size_t)bh * GC * 64 + tid;
    for (int j = 0; j < GC; ++j) s += pp[j * 64];
    sums[tid] = s;  // S[c*8+e]
  } else if (tid < 72) {
    const int e = tid - 64;
    float s = 0.f;
    const float* pp = nkp + ((size_t)b * 64 + head * 8 + e) * 64;
    for (int j = 0; j < 64; ++j) s += pp[j];
    sums[64 + e] = s;  // nk[e]
  } else if (tid < 80) {
    const int c = tid - 72;
    float s = 0.f;
    const float* pp = nqp + ((size_t)b * 64 + head * 8 + c) * 64;
    for (int j = 0; j < 64; ++j) s += pp[j];
    sums[72 + c] = s;  // nq[c]
  }
  __syncthreads();
  if (tid < 8) {
    const int c = tid;
    float tp = temp[head];
    float qd = fmaxf(sqrtf(sums[72 + c]), 1e-12f);
    float vals[8];
    float mx = -1e30f;
#pragma unroll
    for (int e = 0; e < 8; ++e) {
      float kd = fmaxf(sqrtf(sums[64 + e]), 1e-12f);
      vals[e] = sums[c * 8 + e] / (qd * kd) * tp;
      mx = fmaxf(mx, vals[e]);
    }
    float den = 0.f;
#pragma unroll
    for (int e = 0; e < 8; ++e) { vals[e] = expf(vals[e] - mx); den += vals[e]; }
#pragma unroll
    for (int e = 0; e < 8; ++e) A[bh * 64 + c * 8 + e] = vals[e] / den;
  }
}

// ---------------------------------------------------------------------------
// k_M: fold softmax(A) into W_proj -> MT[b][g][o] (transposed for s_load).
// ---------------------------------------------------------------------------
__global__ void k_M(const float* __restrict__ w_proj, const float* __restrict__ A,
                    float* __restrict__ MT) {
  const int b = blockIdx.x;
  for (int e = threadIdx.x; e < 4096; e += 256) {
    int o = e >> 6, gch = e & 63;
    int hg = gch >> 3, j = gch & 7;
    float s = 0.f;
#pragma unroll
    for (int i = 0; i < 8; ++i)
      s += w_proj[o * 64 + hg * 8 + i] * A[(b * 8 + hg) * 64 + i * 8 + j];
    MT[b * 4096 + gch * 64 + o] = s;
  }
}

// ---------------------------------------------------------------------------
// k_out: out[b][o][p] = sum_g MT[b][g][o] * vconv[b][g][p]. grid (512, 2).
// ---------------------------------------------------------------------------
__global__ __launch_bounds__(256) void k_out(const float* __restrict__ vconv,
                                             const float* __restrict__ MT,
                                             float* __restrict__ out) {
  const int p = blockIdx.x * 256 + threadIdx.x;
  const int b = blockIdx.y;
  float acc[64];
#pragma unroll
  for (int o = 0; o < 64; ++o) acc[o] = 0.f;
  const float* vb = vconv + ((size_t)b * 64) * NPOS + p;
  const float* Mb = MT + b * 4096;
  for (int g = 0; g < 64; ++g) {
    float vv = vb[(size_t)g * NPOS];
    const float* wr = Mb + (g << 6);
#pragma unroll
    for (int o = 0; o < 64; ++o) acc[o] = fmaf(wr[o], vv, acc[o]);
  }
  float* ob = out + ((size_t)b * 64) * NPOS + p;
#pragma unroll
  for (int o = 0; o < 64; ++o) ob[(size_t)o * NPOS] = acc[o];
}

extern "C" void kernel_launch(void* const* d_in, const int* in_sizes, int n_in,
                              void* d_out, int out_size, void* d_ws, size_t ws_size,
                              hipStream_t stream) {
  const float* x      = (const float*)d_in[0];
  const float* w_qkv  = (const float*)d_in[1];
  const float* w_dw   = (const float*)d_in[2];
  const float* temp   = (const float*)d_in[3];
  const float* w_proj = (const float*)d_in[4];
  float* out = (float*)d_out;   // also used as pre-conv staging per group
  float* ws  = (float*)d_ws;

  // workspace layout (floats) — ~135 MB (ws_size ~256 MiB: r9/r10 proven fit)
  float* conv_buf = ws;                       // qconv, later vconv (67 MB)
  float* kconv    = conv_buf + 16777216ull;   // 67 MB
  float* nqp      = kconv + 16777216ull;      // 8,192
  float* nkp      = nqp + 8192ull;            // 8,192
  float* partialS = nkp + 8192ull;            // 16*GC*64 = 131,072
  float* Abuf     = partialS + 131072ull;     // 1,024
  float* MTbuf    = Abuf + 1024ull;           // 8,192
  float* wTbuf    = MTbuf + 8192ull;          // 12,288

  k_prep<<<2, 256, 0, stream>>>(w_qkv, wTbuf);
  // q group: pointwise -> d_out, depthwise -> conv_buf (+ nq partials)
  k_pw<<<dim3(512, 2), 256, 0, stream>>>(x, wTbuf, out);
  k_dw<<<8192, dim3(32, 8), 0, stream>>>(out, w_dw, conv_buf, nqp, 0);
  // k group: pointwise -> d_out, depthwise -> kconv (+ nk partials)
  k_pw<<<dim3(512, 2), 256, 0, stream>>>(x, wTbuf + 4096, out);
  k_dw<<<8192, dim3(32, 8), 0, stream>>>(out, w_dw, kconv, nkp, 1);
  // Gram + attention matrix + folded projection matrix
  k_gramS<<<dim3(GC, 16), 256, 0, stream>>>(conv_buf, kconv, partialS);
  k_attn<<<16, 128, 0, stream>>>(partialS, nqp, nkp, temp, Abuf);
  k_M<<<2, 256, 0, stream>>>(w_proj, Abuf, MTbuf);
  // v group: pointwise -> d_out, depthwise -> conv_buf, apply M -> d_out
  k_pw<<<dim3(512, 2), 256, 0, stream>>>(x, wTbuf + 8192, out);
  k_dw<<<8192, dim3(32, 8), 0, stream>>>(out, w_dw, conv_buf, nullptr, 2);
  k_out<<<dim3(512, 2), 256, 0, stream>>>(conv_buf, MTbuf, out);
}